// Round 3
// baseline (110.083 us; speedup 1.0000x reference)
//
#include <hip/hip_runtime.h>
#include <type_traits>

// PopulationCoding, round 14 (= r13 resubmit; r13 bench died on container
// infra, no counters). r12: split-f16 MFMA GEMM landed (123->109us).
// Fill fixed ~42us. Ours ~67: prep ~5 + mfma ~20 + epi ~42 (dominant).
//  Epi theory: conv LUT reads are byte-indexed 256x16B tables -> bank group
//  b%8 -> ~8-way conflicts (2.94x, m136) on 48 b128 reads/thread + random
//  rlut scalar reads. This round:
//   - nibble-split LUTs: 6 reads/t from 16x16B tables (256B spans banks 2x ->
//     max 2 distinct addr/bank = FREE 2-way aliasing) + broadcasts.
//   - rate branch via exact bit-plane popcount of own nibbles (rlut gone).
//   - LUT build 3072 -> 384 entries; epi LDS 17.5KB -> ~6KB.
//   - mfma grid: bijective XCD swizzle (512=8x64) -> 4 N-tiles/XCD, A+B
//     slices L2-resident.
// B=1024, IN=512, D=256, P=8, T=32. Output [1024,256] fp32.

constexpr int IN_DIM  = 512;
constexpr int D_DIM   = 256;
constexpr int NTOT    = 2048;   // D*P
constexpr int T_STEPS = 32;

typedef _Float16 f16x8 __attribute__((ext_vector_type(8)));
typedef float    f32x4 __attribute__((ext_vector_type(4)));
typedef ushort   ushort8 __attribute__((ext_vector_type(8)));

#define GLOBAL_AS __attribute__((address_space(1)))
#define LDS_AS    __attribute__((address_space(3)))

__device__ __forceinline__ void split_f16(float v, ushort& h, ushort& l) {
    const _Float16 hf = (_Float16)v;
    const _Float16 lf = (_Float16)((v - (float)hf) * 2048.0f);  // lo pre-scaled 2^11
    h = __builtin_bit_cast(ushort, hf);
    l = __builtin_bit_cast(ushort, lf);
}

// ------------------------------------------------- K0: split-f16 conversion
// blocks 0..255:   x [1024][512] -> Ah/Al [1024][512] (8 elems/thread)
// blocks 256..511: Wp [512][2048] -> Bh/Bl [2048][512] (64x64 LDS transpose)
__global__ __launch_bounds__(256)
void popcode_prep(const float* __restrict__ x, const float* __restrict__ Wp,
                  ushort* __restrict__ Ah, ushort* __restrict__ Al,
                  ushort* __restrict__ Bh, ushort* __restrict__ Bl)
{
    __shared__ float tile[64][68];
    const int t = threadIdx.x;
    if (blockIdx.x < 256) {
        const int idx = (blockIdx.x * 256 + t) * 8;
        float v[8];
        *reinterpret_cast<float4*>(v)     = *reinterpret_cast<const float4*>(x + idx);
        *reinterpret_cast<float4*>(v + 4) = *reinterpret_cast<const float4*>(x + idx + 4);
        __align__(16) ushort h[8], l[8];
#pragma unroll
        for (int j = 0; j < 8; ++j) split_f16(v[j], h[j], l[j]);
        *reinterpret_cast<ushort8*>(Ah + idx) = *reinterpret_cast<const ushort8*>(h);
        *reinterpret_cast<ushort8*>(Al + idx) = *reinterpret_cast<const ushort8*>(l);
    } else {
        const int ib = blockIdx.x - 256;
        const int k0 = (ib >> 5) * 64;          // 8 k-tiles
        const int c0 = (ib & 31) * 64;          // 32 col-tiles
        {
            const int r = t >> 2, cq = (t & 3) * 16;
#pragma unroll
            for (int j = 0; j < 4; ++j)
                *reinterpret_cast<float4*>(&tile[r][cq + j * 4]) =
                    *reinterpret_cast<const float4*>(Wp + (size_t)(k0 + r) * NTOT + c0 + cq + j * 4);
        }
        __syncthreads();
        const int c = t & 63, kq = (t >> 6) * 16;
        __align__(16) ushort h[16], l[16];
#pragma unroll
        for (int j = 0; j < 16; ++j) split_f16(tile[kq + j][c], h[j], l[j]);
        ushort* dh = Bh + (size_t)(c0 + c) * 512 + k0 + kq;
        ushort* dl = Bl + (size_t)(c0 + c) * 512 + k0 + kq;
        *reinterpret_cast<ushort8*>(dh)     = *reinterpret_cast<const ushort8*>(h);
        *reinterpret_cast<ushort8*>(dh + 8) = *reinterpret_cast<const ushort8*>(h + 8);
        *reinterpret_cast<ushort8*>(dl)     = *reinterpret_cast<const ushort8*>(l);
        *reinterpret_cast<ushort8*>(dl + 8) = *reinterpret_cast<const ushort8*>(l + 8);
    }
}

// --------------------------------------------------- K1: split-f16 MFMA GEMM
// 512 blocks (1D, XCD-swizzled), 256 threads (4 waves). Tile 64x64, BK=32.
// Wave w: plane w stager (Ah/Al/Bh/Bl) + 32x32 output quadrant.
__global__ __launch_bounds__(256, 2)
void popcode_mfma(const ushort* __restrict__ Ah_g, const ushort* __restrict__ Al_g,
                  const ushort* __restrict__ Bh_g, const ushort* __restrict__ Bl_g,
                  float* __restrict__ Iout)
{
    __shared__ __align__(16) ushort Lds[2][4][64][32];   // [buf][plane][row][k] 32 KB

    const int tid  = threadIdx.x;
    const int w    = tid >> 6;          // wave id = staged plane id
    const int lane = tid & 63;

    // bijective XCD swizzle: 512 = 8 XCDs x 64 contiguous wgs.
    // 64 consecutive wgs = 4 full N-tiles x 16 M-tiles -> A(2MB)+B(0.5MB)
    // slices fit one XCD L2.
    const int wg = (blockIdx.x & 7) * 64 + (blockIdx.x >> 3);
    const int b0 = (wg & 15) * 64;      // M tile (batch rows)
    const int c0 = (wg >> 4) * 64;      // N tile (neuron cols)

    // staging: lane covers rows (lane>>2)+16i, 16B chunk (lane&3)
    const ushort* gbase = (w == 0) ? Ah_g : (w == 1) ? Al_g : (w == 2) ? Bh_g : Bl_g;
    const int     t0    = (w < 2) ? b0 : c0;
    const int     srow  = lane >> 2;
    const int     schk  = (lane & 3) * 8;     // in halves

    const int wr = (w >> 1) * 32;       // quadrant row origin
    const int wc = (w & 1) * 32;        // quadrant col origin
    const int lr = lane & 15;
    const int lg = lane >> 4;           // k-group / output row group

    const f32x4 zero = {0.f, 0.f, 0.f, 0.f};
    f32x4 acch[2][2] = {{zero, zero}, {zero, zero}};
    f32x4 accl[2][2] = {{zero, zero}, {zero, zero}};

    LDS_AS char* lds0 = (LDS_AS char*)&Lds[0][0][0][0];

    auto stage = [&](int buf, int kt) {
        const int koff = kt * 32 + schk;
#pragma unroll
        for (int i = 0; i < 4; ++i) {
            const ushort* src = gbase + (size_t)(t0 + srow + 16 * i) * 512 + koff;
            const int loff = __builtin_amdgcn_readfirstlane(buf * 16384 + w * 4096 + i * 1024);
            __builtin_amdgcn_global_load_lds((const GLOBAL_AS uint*)src,
                                             (LDS_AS uint*)(lds0 + loff), 16, 0, 0);
        }
    };

    auto compute = [&](int buf) {
        f16x8 ah[2], al[2], bh[2], bl[2];
#pragma unroll
        for (int m = 0; m < 2; ++m) {
            const int row = wr + m * 16 + lr;
            ah[m] = *(const f16x8*)&Lds[buf][0][row][lg * 8];
            al[m] = *(const f16x8*)&Lds[buf][1][row][lg * 8];
        }
#pragma unroll
        for (int n = 0; n < 2; ++n) {
            const int col = wc + n * 16 + lr;
            bh[n] = *(const f16x8*)&Lds[buf][2][col][lg * 8];
            bl[n] = *(const f16x8*)&Lds[buf][3][col][lg * 8];
        }
#pragma unroll
        for (int m = 0; m < 2; ++m)
#pragma unroll
            for (int n = 0; n < 2; ++n) {
                acch[m][n] = __builtin_amdgcn_mfma_f32_16x16x32_f16(ah[m], bh[n], acch[m][n], 0, 0, 0);
                accl[m][n] = __builtin_amdgcn_mfma_f32_16x16x32_f16(al[m], bh[n], accl[m][n], 0, 0, 0);
                accl[m][n] = __builtin_amdgcn_mfma_f32_16x16x32_f16(ah[m], bl[n], accl[m][n], 0, 0, 0);
            }
    };

    stage(0, 0);
    __syncthreads();                     // compiler drains vmcnt before barrier
    for (int kt = 0; kt < 16; ++kt) {
        if (kt < 15) stage((kt + 1) & 1, kt + 1);   // async into other buffer
        compute(kt & 1);
        __syncthreads();
    }

    // C/D layout (m89-verified): col = lane&15, row = (lane>>4)*4 + v
    const float s = 1.0f / 2048.0f;
#pragma unroll
    for (int m = 0; m < 2; ++m)
#pragma unroll
        for (int n = 0; n < 2; ++n) {
            float* dst = Iout + (size_t)(b0 + wr + m * 16 + lg * 4) * NTOT
                              + c0 + wc + n * 16 + lr;
#pragma unroll
            for (int v = 0; v < 4; ++v)
                dst[(size_t)v * NTOT] = acch[m][n][v] + accl[m][n][v] * s;
        }
}

// ------------------------------------------------------------ K2: epilogue
// 2 threads per neuron: waves (0,1) and (2,3) are partner pairs (thread tid
// partners tid^64). h = wave&1 selects p-half (LIF) and t-half (conv).
// Conv via nibble-split LUTs (conflict-free); rate via bit-plane popcount.
__global__ __launch_bounds__(256)
void popcode_epi(const float* __restrict__ Iin,
                 const float* __restrict__ bp,
                 const float* __restrict__ thrs,
                 const float* __restrict__ rateW,
                 const float* __restrict__ rateB,
                 const float* __restrict__ c1w,
                 const float* __restrict__ c1b,
                 const float* __restrict__ c2w,
                 const float* __restrict__ c2b,
                 const float* __restrict__ fus,
                 float* __restrict__ out)
{
    __shared__ float lut[3][2][16][4];   // [tap][half][nib][chan] 1.5 KB
    __shared__ float wlds[96];
    __shared__ uint4 exch[256];          // 4 KB nibble exchange / partial sums

    const int tid = threadIdx.x;
    const int wv  = tid >> 6;
    const int h   = wv & 1;                         // wave-uniform
    const int nl  = ((wv >> 1) << 6) | (tid & 63);  // 0..127
    const int n   = blockIdx.x * 128 + nl;
    const int b   = n >> 8;
    const int d   = n & 255;

    // ---- build nibble LUTs (once per block) ----
    if (tid < 96) wlds[tid] = c1w[tid];
    __syncthreads();
    for (int e = tid; e < 384; e += 256) {
        const int k  = e >> 7;           // tap 0..2
        const int j  = (e >> 6) & 1;     // p-half
        const int nb = (e >> 2) & 15;    // nibble
        const int c  = e & 3;            // channel
        float v = (k == 1 && j == 0) ? c1b[c] : 0.f;  // fold conv1 bias once
#pragma unroll
        for (int p = 0; p < 4; ++p)
            v = fmaf((float)((nb >> p) & 1), wlds[(c * 8 + j * 4 + p) * 3 + k], v);
        (&lut[0][0][0][0])[e] = v;
    }

    // ---- uniform scalars ----
    float w2c[4];
#pragma unroll
    for (int c = 0; c < 4; ++c) w2c[c] = c2w[c];
    float rW[4];
#pragma unroll
    for (int p = 0; p < 4; ++p) rW[p] = rateW[h * 4 + p];
    const float rb_ = rateB[0];
    const float bb2 = c2b[0];
    const float f0 = fus[0], f1 = fus[1];
    const float fm = fmaxf(f0, f1);
    const float e0 = __expf(f0 - fm), e1 = __expf(f1 - fm);
    const float inv = 1.f / (e0 + e1);
    const float fw0 = e0 * inv, fw1 = e1 * inv;

    // ---- gather I for this thread's 4 p's ----
    const size_t base = (size_t)b * NTOT + d * 8 + h * 4;
    const float4 iv   = *reinterpret_cast<const float4*>(Iin + base);
    const float4 bpv  = *reinterpret_cast<const float4*>(bp + d * 8 + h * 4);
    const float4 tv   = *reinterpret_cast<const float4*>(thrs + h * 4);
    float Iv[4]  = {iv.x + bpv.x, iv.y + bpv.y, iv.z + bpv.z, iv.w + bpv.w};
    float thr[4] = {tv.x, tv.y, tv.z, tv.w};
    float Imt[4], mem[4];
    bool  spk[4];
#pragma unroll
    for (int p = 0; p < 4; ++p) {
        Imt[p] = Iv[p] - thr[p];
        mem[p] = 0.f;
        spk[p] = false;
    }

    // ---- LIF for 4 p's, packing a nibble per t (8 t per u32) ----
    unsigned nib[4] = {0u, 0u, 0u, 0u};
#pragma unroll
    for (int t = 0; t < T_STEPS; ++t) {
        unsigned nb = 0u;
#pragma unroll
        for (int p = 0; p < 4; ++p) {
            mem[p] = 0.95f * mem[p] + (spk[p] ? Imt[p] : Iv[p]);
            spk[p] = mem[p] > thr[p];
            nb |= spk[p] ? (1u << p) : 0u;
        }
        nib[t >> 3] |= nb << (4 * (t & 7));
    }

    // ---- rate branch: exact bit-plane popcount over own 4 p's, all 32 t ----
    float rsum = 0.f;
#pragma unroll
    for (int p = 0; p < 4; ++p) {
        const unsigned m = 0x11111111u << p;
        const int cnt = __popc(nib[0] & m) + __popc(nib[1] & m)
                      + __popc(nib[2] & m) + __popc(nib[3] & m);
        rsum = fmaf((float)cnt, rW[p], rsum);
    }

    // ---- exchange nibbles with the partner thread (other wave) ----
    __syncthreads();   // lut build + exch ready
    exch[tid] = uint4{nib[0], nib[1], nib[2], nib[3]};
    __syncthreads();
    const uint4 pr = exch[tid ^ 64];
    const unsigned prn[4] = {pr.x, pr.y, pr.z, pr.w};
    unsigned lo[4], hi[4];
#pragma unroll
    for (int w = 0; w < 4; ++w) {
        lo[w] = h ? prn[w] : nib[w];   // p0..3 half
        hi[w] = h ? nib[w] : prn[w];   // p4..7 half
    }

    // ---- conv over this thread's half of the t-range ----
    auto getn = [&](int t, const unsigned* a) -> unsigned {
        return (a[t >> 3] >> (4 * (t & 7))) & 15u;
    };
    const float* lutf = &lut[0][0][0][0];
    float tacc = 0.f;

    auto conv_half = [&](auto T0C) {
        constexpr int T0 = T0C.value;
        unsigned nlp = (T0 == 0) ? 0u : getn(T0 - 1, lo);
        unsigned nhp = (T0 == 0) ? 0u : getn(T0 - 1, hi);
        unsigned nlc = getn(T0, lo);
        unsigned nhc = getn(T0, hi);
#pragma unroll
        for (int i = 0; i < 16; ++i) {
            const int t = T0 + i;
            const unsigned nln = (t < 31) ? getn(t + 1, lo) : 0u;
            const unsigned nhn = (t < 31) ? getn(t + 1, hi) : 0u;
            // 6 reads from 16x16B tables: <=2 distinct addr/bank -> free
            const float4 a0 = *reinterpret_cast<const float4*>(lutf + (nlp     ) * 4);
            const float4 a1 = *reinterpret_cast<const float4*>(lutf + (nhp + 16) * 4);
            const float4 b0 = *reinterpret_cast<const float4*>(lutf + (nlc + 32) * 4);
            const float4 b1 = *reinterpret_cast<const float4*>(lutf + (nhc + 48) * 4);
            const float4 c0 = *reinterpret_cast<const float4*>(lutf + (nln + 64) * 4);
            const float4 c1 = *reinterpret_cast<const float4*>(lutf + (nhn + 80) * 4);
            const float h0_ = ((a0.x + a1.x) + (b0.x + b1.x)) + (c0.x + c1.x);
            const float h1_ = ((a0.y + a1.y) + (b0.y + b1.y)) + (c0.y + c1.y);
            const float h2_ = ((a0.z + a1.z) + (b0.z + b1.z)) + (c0.z + c1.z);
            const float h3_ = ((a0.w + a1.w) + (b0.w + b1.w)) + (c0.w + c1.w);
            tacc = fmaf(fmaxf(h0_, 0.f), w2c[0], tacc);
            tacc = fmaf(fmaxf(h1_, 0.f), w2c[1], tacc);
            tacc = fmaf(fmaxf(h2_, 0.f), w2c[2], tacc);
            tacc = fmaf(fmaxf(h3_, 0.f), w2c[3], tacc);
            nlp = nlc; nhp = nhc; nlc = nln; nhc = nhn;
        }
    };
    if (h == 0) conv_half(std::integral_constant<int, 0>{});
    else        conv_half(std::integral_constant<int, 16>{});

    // ---- combine partner partial sums, write ----
    __syncthreads();   // all exch reads done
    float2* e2 = reinterpret_cast<float2*>(exch);
    e2[tid] = float2{rsum, tacc};
    __syncthreads();
    const float2 q = e2[tid ^ 64];
    rsum += q.x;
    tacc += q.y;

    if (h == 0) {
        const float rdec = rsum * (1.f / 32.f) + rb_;
        const float temp = tacc * (1.f / 32.f) + bb2;
        out[b * D_DIM + d] = fw0 * rdec + fw1 * temp;
    }
}

extern "C" void kernel_launch(void* const* d_in, const int* in_sizes, int n_in,
                              void* d_out, int out_size, void* d_ws, size_t ws_size,
                              hipStream_t stream) {
    const float* x     = (const float*)d_in[0];
    const float* Wp    = (const float*)d_in[1];
    const float* bp    = (const float*)d_in[2];
    const float* thrs  = (const float*)d_in[3];
    const float* rateW = (const float*)d_in[4];
    const float* rateB = (const float*)d_in[5];
    const float* c1w   = (const float*)d_in[6];
    const float* c1b   = (const float*)d_in[7];
    const float* c2w   = (const float*)d_in[8];
    const float* c2b   = (const float*)d_in[9];
    const float* fus   = (const float*)d_in[10];
    float* out = (float*)d_out;
    float* ws  = (float*)d_ws;

    // ws layout: Ah[1024*512]u16 | Al | Bh[2048*512]u16 | Bl | I[1024*2048]f32
    ushort* Ah = reinterpret_cast<ushort*>(ws);
    ushort* Al = Ah + 1024 * 512;
    ushort* Bh = Al + 1024 * 512;
    ushort* Bl = Bh + 2048 * 512;
    float*  I  = ws + 1536 * 1024;        // 6 MB offset

    popcode_prep<<<dim3(512), dim3(256), 0, stream>>>(x, Wp, Ah, Al, Bh, Bl);
    popcode_mfma<<<dim3(512), dim3(256), 0, stream>>>(Ah, Al, Bh, Bl, I);
    popcode_epi<<<dim3(2048), dim3(256), 0, stream>>>(
        I, bp, thrs, rateW, rateB, c1w, c1b, c2w, c2b, fus, out);
}

// Round 4
// 106.572 us; speedup vs baseline: 1.0329x; 1.0329x over previous
//
#include <hip/hip_runtime.h>

// PopulationCoding, round 15.
//  r13/r14 post-mortem: conflict-free LUT conv = NULL (110.1 vs 109.0).
//  r12's byte-LUT was only ~2.2x conflicted on 3 reads ~= 6 clean reads ->
//  epi never was conflict-bound. 4th conv variant at same time => cost is
//  structural (3 serialized launches, 16MB I round-trip, ramps), invisible
//  to top-5 counters (every kernel < 41us fill).
//  r15: FUSE gemm+epi. 64x64 I-tile = 64 batch x 8 full neurons -> LIF+conv
//  in-block via Itile in LDS (65-pad). Drops I traffic (16MB), one launch,
//  partner/exch machinery. Also fix prep B-transpose writes (were 16B/lane
//  at 1KB stride scatter; now coalesced 32B/thread).
// B=1024, IN=512, D=256, P=8, T=32. Output [1024,256] fp32.

constexpr int IN_DIM  = 512;
constexpr int D_DIM   = 256;
constexpr int NTOT    = 2048;   // D*P
constexpr int T_STEPS = 32;

typedef _Float16 f16x8 __attribute__((ext_vector_type(8)));
typedef float    f32x4 __attribute__((ext_vector_type(4)));
typedef ushort   ushort8 __attribute__((ext_vector_type(8)));

#define GLOBAL_AS __attribute__((address_space(1)))
#define LDS_AS    __attribute__((address_space(3)))

__device__ __forceinline__ void split_f16(float v, ushort& h, ushort& l) {
    const _Float16 hf = (_Float16)v;
    const _Float16 lf = (_Float16)((v - (float)hf) * 2048.0f);  // lo pre-scaled 2^11
    h = __builtin_bit_cast(ushort, hf);
    l = __builtin_bit_cast(ushort, lf);
}

// ------------------------------------------------- K0: split-f16 conversion
// blocks 0..255:   x [1024][512] -> Ah/Al [1024][512] (8 elems/thread)
// blocks 256..511: Wp [512][2048] -> Bh/Bl [2048][512] (64x64 LDS transpose,
//                  coalesced writes: thread t owns B-row t>>2, k-chunk t&3)
__global__ __launch_bounds__(256)
void popcode_prep(const float* __restrict__ x, const float* __restrict__ Wp,
                  ushort* __restrict__ Ah, ushort* __restrict__ Al,
                  ushort* __restrict__ Bh, ushort* __restrict__ Bl)
{
    __shared__ float tile[64][69];   // 69-pad: transpose reads <=2-way banked
    const int t = threadIdx.x;
    if (blockIdx.x < 256) {
        const int idx = (blockIdx.x * 256 + t) * 8;
        float v[8];
        *reinterpret_cast<float4*>(v)     = *reinterpret_cast<const float4*>(x + idx);
        *reinterpret_cast<float4*>(v + 4) = *reinterpret_cast<const float4*>(x + idx + 4);
        __align__(16) ushort h[8], l[8];
#pragma unroll
        for (int j = 0; j < 8; ++j) split_f16(v[j], h[j], l[j]);
        *reinterpret_cast<ushort8*>(Ah + idx) = *reinterpret_cast<const ushort8*>(h);
        *reinterpret_cast<ushort8*>(Al + idx) = *reinterpret_cast<const ushort8*>(l);
    } else {
        const int ib = blockIdx.x - 256;
        const int k0 = (ib >> 5) * 64;          // 8 k-tiles
        const int c0 = (ib & 31) * 64;          // 32 col-tiles
        {
            const int r = t >> 2, cq = (t & 3) * 16;
#pragma unroll
            for (int j = 0; j < 4; ++j)
                *reinterpret_cast<float4*>(&tile[r][cq + j * 4]) =
                    *reinterpret_cast<const float4*>(Wp + (size_t)(k0 + r) * NTOT + c0 + cq + j * 4);
        }
        __syncthreads();
        // thread t: B row rr = t>>2 (0..63), k-chunk kc2 = (t&3)*16
        const int rr = t >> 2, kc2 = (t & 3) * 16;
        __align__(16) ushort h[16], l[16];
#pragma unroll
        for (int j = 0; j < 16; ++j) split_f16(tile[kc2 + j][rr], h[j], l[j]);
        ushort* dh = Bh + (size_t)(c0 + rr) * 512 + k0 + kc2;
        ushort* dl = Bl + (size_t)(c0 + rr) * 512 + k0 + kc2;
        *reinterpret_cast<ushort8*>(dh)     = *reinterpret_cast<const ushort8*>(h);
        *reinterpret_cast<ushort8*>(dh + 8) = *reinterpret_cast<const ushort8*>(h + 8);
        *reinterpret_cast<ushort8*>(dl)     = *reinterpret_cast<const ushort8*>(l);
        *reinterpret_cast<ushort8*>(dl + 8) = *reinterpret_cast<const ushort8*>(l + 8);
    }
}

// ------------------------------------- K1: fused split-f16 MFMA GEMM + epi
// 512 blocks (XCD-swizzled), 256 threads (4 waves). Tile 64x64, BK=32.
// GEMM phase: wave w stages plane w, computes 32x32 quadrant.
// Then acc -> Itile (LDS, 65-pad) -> each thread runs 2 full neurons
// (8-chain LIF, popcount rate, full-32t nibble-LUT conv).
__global__ __launch_bounds__(256, 2)
void popcode_fused(const ushort* __restrict__ Ah_g, const ushort* __restrict__ Al_g,
                   const ushort* __restrict__ Bh_g, const ushort* __restrict__ Bl_g,
                   const float* __restrict__ bp,
                   const float* __restrict__ thrs,
                   const float* __restrict__ rateW,
                   const float* __restrict__ rateB,
                   const float* __restrict__ c1w,
                   const float* __restrict__ c1b,
                   const float* __restrict__ c2w,
                   const float* __restrict__ c2b,
                   const float* __restrict__ fus,
                   float* __restrict__ out)
{
    __shared__ __align__(16) ushort Lds[2][4][64][32];   // 32 KB staging
    __shared__ float Itile[64][65];                      // 16.6 KB, 65-pad
    __shared__ float lut[3][2][16][4];                   // 1.5 KB
    __shared__ float wlds[96];

    const int tid  = threadIdx.x;
    const int w    = tid >> 6;          // wave id = staged plane id
    const int lane = tid & 63;

    // bijective XCD swizzle: 512 = 8 XCDs x 64 contiguous wgs.
    const int wg = (blockIdx.x & 7) * 64 + (blockIdx.x >> 3);
    const int b0 = (wg & 15) * 64;      // M tile (batch rows)
    const int c0 = (wg >> 4) * 64;      // N tile (neuron cols)

    const ushort* gbase = (w == 0) ? Ah_g : (w == 1) ? Al_g : (w == 2) ? Bh_g : Bl_g;
    const int     t0    = (w < 2) ? b0 : c0;
    const int     srow  = lane >> 2;
    const int     schk  = (lane & 3) * 8;     // in halves

    const int wr = (w >> 1) * 32;       // quadrant row origin
    const int wc = (w & 1) * 32;        // quadrant col origin
    const int lr = lane & 15;
    const int lg = lane >> 4;           // k-group / output row group

    const f32x4 zero = {0.f, 0.f, 0.f, 0.f};
    f32x4 acch[2][2] = {{zero, zero}, {zero, zero}};
    f32x4 accl[2][2] = {{zero, zero}, {zero, zero}};

    LDS_AS char* lds0 = (LDS_AS char*)&Lds[0][0][0][0];

    auto stage = [&](int buf, int kt) {
        const int koff = kt * 32 + schk;
#pragma unroll
        for (int i = 0; i < 4; ++i) {
            const ushort* src = gbase + (size_t)(t0 + srow + 16 * i) * 512 + koff;
            const int loff = __builtin_amdgcn_readfirstlane(buf * 16384 + w * 4096 + i * 1024);
            __builtin_amdgcn_global_load_lds((const GLOBAL_AS uint*)src,
                                             (LDS_AS uint*)(lds0 + loff), 16, 0, 0);
        }
    };

    auto compute = [&](int buf) {
        f16x8 ah[2], al[2], bh[2], bl[2];
#pragma unroll
        for (int m = 0; m < 2; ++m) {
            const int row = wr + m * 16 + lr;
            ah[m] = *(const f16x8*)&Lds[buf][0][row][lg * 8];
            al[m] = *(const f16x8*)&Lds[buf][1][row][lg * 8];
        }
#pragma unroll
        for (int n = 0; n < 2; ++n) {
            const int col = wc + n * 16 + lr;
            bh[n] = *(const f16x8*)&Lds[buf][2][col][lg * 8];
            bl[n] = *(const f16x8*)&Lds[buf][3][col][lg * 8];
        }
#pragma unroll
        for (int m = 0; m < 2; ++m)
#pragma unroll
            for (int n = 0; n < 2; ++n) {
                acch[m][n] = __builtin_amdgcn_mfma_f32_16x16x32_f16(ah[m], bh[n], acch[m][n], 0, 0, 0);
                accl[m][n] = __builtin_amdgcn_mfma_f32_16x16x32_f16(al[m], bh[n], accl[m][n], 0, 0, 0);
                accl[m][n] = __builtin_amdgcn_mfma_f32_16x16x32_f16(ah[m], bl[n], accl[m][n], 0, 0, 0);
            }
    };

    // ---- prologue: wlds + first stage; LUT build overlaps load latency ----
    if (tid < 96) wlds[tid] = c1w[tid];
    stage(0, 0);
    __syncthreads();                 // wlds visible; buf0 staged (vmcnt drained)

    for (int e = tid; e < 384; e += 256) {
        const int k  = e >> 7;           // tap 0..2
        const int j  = (e >> 6) & 1;     // p-half
        const int nb = (e >> 2) & 15;    // nibble
        const int c  = e & 3;            // channel
        float v = (k == 1 && j == 0) ? c1b[c] : 0.f;  // fold conv1 bias once
#pragma unroll
        for (int p = 0; p < 4; ++p)
            v = fmaf((float)((nb >> p) & 1), wlds[(c * 8 + j * 4 + p) * 3 + k], v);
        (&lut[0][0][0][0])[e] = v;
    }

    // ---- GEMM k-loop ----
    for (int kt = 0; kt < 16; ++kt) {
        if (kt < 15) stage((kt + 1) & 1, kt + 1);
        compute(kt & 1);
        __syncthreads();
    }

    // ---- acc -> Itile (C/D layout: col = lane&15, row = (lane>>4)*4 + v) ----
    const float s = 1.0f / 2048.0f;
#pragma unroll
    for (int m = 0; m < 2; ++m)
#pragma unroll
        for (int n = 0; n < 2; ++n)
#pragma unroll
            for (int v = 0; v < 4; ++v)
                Itile[wr + m * 16 + lg * 4 + v][wc + n * 16 + lr] =
                    acch[m][n][v] + accl[m][n][v] * s;
    __syncthreads();

    // ---- uniform scalars ----
    float w2c[4];
#pragma unroll
    for (int c = 0; c < 4; ++c) w2c[c] = c2w[c];
    float rW[8], thrv[8];
#pragma unroll
    for (int p = 0; p < 8; ++p) { rW[p] = rateW[p]; thrv[p] = thrs[p]; }
    const float rb_ = rateB[0];
    const float bb2 = c2b[0];
    const float f0 = fus[0], f1 = fus[1];
    const float fm = fmaxf(f0, f1);
    const float e0 = __expf(f0 - fm), e1 = __expf(f1 - fm);
    const float inv = 1.f / (e0 + e1);
    const float fw0 = e0 * inv, fw1 = e1 * inv;

    const float* lutf = &lut[0][0][0][0];

    // ---- epilogue: 2 full neurons per thread ----
    for (int half = 0; half < 2; ++half) {
        const int nb   = tid + half * 256;   // 0..511
        const int row  = nb >> 3;            // batch-local 0..63
        const int dloc = nb & 7;
        const int dg   = (c0 >> 3) + dloc;   // global d

        const float* ip = &Itile[row][dloc * 8];
        const float4 bv0 = *reinterpret_cast<const float4*>(bp + dg * 8);
        const float4 bv1 = *reinterpret_cast<const float4*>(bp + dg * 8 + 4);
        const float bpx[8] = {bv0.x, bv0.y, bv0.z, bv0.w, bv1.x, bv1.y, bv1.z, bv1.w};

        float Iv[8], Imt[8], mem[8];
        bool  spk[8];
#pragma unroll
        for (int p = 0; p < 8; ++p) {
            Iv[p]  = ip[p] + bpx[p];         // scalar LDS reads (<=2-way banked)
            Imt[p] = Iv[p] - thrv[p];
            mem[p] = 0.f;
            spk[p] = false;
        }

        unsigned nibL[4] = {0u, 0u, 0u, 0u}, nibH[4] = {0u, 0u, 0u, 0u};
#pragma unroll
        for (int t = 0; t < T_STEPS; ++t) {
            unsigned bl_ = 0u, bh_ = 0u;
#pragma unroll
            for (int p = 0; p < 8; ++p) {
                mem[p] = 0.95f * mem[p] + (spk[p] ? Imt[p] : Iv[p]);
                spk[p] = mem[p] > thrv[p];
            }
#pragma unroll
            for (int p = 0; p < 4; ++p) bl_ |= spk[p] ? (1u << p) : 0u;
#pragma unroll
            for (int p = 4; p < 8; ++p) bh_ |= spk[p] ? (1u << (p - 4)) : 0u;
            nibL[t >> 3] |= bl_ << (4 * (t & 7));
            nibH[t >> 3] |= bh_ << (4 * (t & 7));
        }

        // rate: exact bit-plane popcount
        float rsum = 0.f;
#pragma unroll
        for (int p = 0; p < 4; ++p) {
            const unsigned m = 0x11111111u << p;
            const int cL = __popc(nibL[0] & m) + __popc(nibL[1] & m)
                         + __popc(nibL[2] & m) + __popc(nibL[3] & m);
            const int cH = __popc(nibH[0] & m) + __popc(nibH[1] & m)
                         + __popc(nibH[2] & m) + __popc(nibH[3] & m);
            rsum = fmaf((float)cL, rW[p], rsum);
            rsum = fmaf((float)cH, rW[4 + p], rsum);
        }

        // conv: full 32-t range, 6 nibble-LUT reads per t
        auto getn = [](const unsigned* a, int t) -> unsigned {
            return (a[t >> 3] >> (4 * (t & 7))) & 15u;
        };
        float tacc = 0.f;
        unsigned nlp = 0u, nhp = 0u;
        unsigned nlc = getn(nibL, 0), nhc = getn(nibH, 0);
#pragma unroll
        for (int t = 0; t < T_STEPS; ++t) {
            const unsigned nln = (t < 31) ? getn(nibL, t + 1) : 0u;
            const unsigned nhn = (t < 31) ? getn(nibH, t + 1) : 0u;
            const float4 a0 = *reinterpret_cast<const float4*>(lutf + (nlp     ) * 4);
            const float4 a1 = *reinterpret_cast<const float4*>(lutf + (nhp + 16) * 4);
            const float4 b0 = *reinterpret_cast<const float4*>(lutf + (nlc + 32) * 4);
            const float4 b1 = *reinterpret_cast<const float4*>(lutf + (nhc + 48) * 4);
            const float4 c0v = *reinterpret_cast<const float4*>(lutf + (nln + 64) * 4);
            const float4 c1v = *reinterpret_cast<const float4*>(lutf + (nhn + 80) * 4);
            const float h0_ = ((a0.x + a1.x) + (b0.x + b1.x)) + (c0v.x + c1v.x);
            const float h1_ = ((a0.y + a1.y) + (b0.y + b1.y)) + (c0v.y + c1v.y);
            const float h2_ = ((a0.z + a1.z) + (b0.z + b1.z)) + (c0v.z + c1v.z);
            const float h3_ = ((a0.w + a1.w) + (b0.w + b1.w)) + (c0v.w + c1v.w);
            tacc = fmaf(fmaxf(h0_, 0.f), w2c[0], tacc);
            tacc = fmaf(fmaxf(h1_, 0.f), w2c[1], tacc);
            tacc = fmaf(fmaxf(h2_, 0.f), w2c[2], tacc);
            tacc = fmaf(fmaxf(h3_, 0.f), w2c[3], tacc);
            nlp = nlc; nhp = nhc; nlc = nln; nhc = nhn;
        }

        const float rdec = rsum * (1.f / 32.f) + rb_;
        const float temp = tacc * (1.f / 32.f) + bb2;
        out[(b0 + row) * D_DIM + dg] = fw0 * rdec + fw1 * temp;
    }
}

extern "C" void kernel_launch(void* const* d_in, const int* in_sizes, int n_in,
                              void* d_out, int out_size, void* d_ws, size_t ws_size,
                              hipStream_t stream) {
    const float* x     = (const float*)d_in[0];
    const float* Wp    = (const float*)d_in[1];
    const float* bp    = (const float*)d_in[2];
    const float* thrs  = (const float*)d_in[3];
    const float* rateW = (const float*)d_in[4];
    const float* rateB = (const float*)d_in[5];
    const float* c1w   = (const float*)d_in[6];
    const float* c1b   = (const float*)d_in[7];
    const float* c2w   = (const float*)d_in[8];
    const float* c2b   = (const float*)d_in[9];
    const float* fus   = (const float*)d_in[10];
    float* out = (float*)d_out;
    float* ws  = (float*)d_ws;

    // ws layout: Ah[1024*512]u16 | Al | Bh[2048*512]u16 | Bl   (12 MB)
    ushort* Ah = reinterpret_cast<ushort*>(ws);
    ushort* Al = Ah + 1024 * 512;
    ushort* Bh = Al + 1024 * 512;
    ushort* Bl = Bh + 2048 * 512;

    popcode_prep<<<dim3(512), dim3(256), 0, stream>>>(x, Wp, Ah, Al, Bh, Bl);
    popcode_fused<<<dim3(512), dim3(256), 0, stream>>>(
        Ah, Al, Bh, Bl, bp, thrs, rateW, rateB, c1w, c1b, c2w, c2b, fus, out);
}